// Round 2
// baseline (93.405 us; speedup 1.0000x reference)
//
#include <hip/hip_runtime.h>
#include <hip/hip_bf16.h>

// NT-Xent (SimCLR) loss, MI355X gfx950.
// loss = (1/N) * sum_i [ ln(S_i - exp2(C1*d_ii)) - (2/C1)*dp_i ]
//   where d = zhat.zhat^T (unit rows), C1 = 2*log2(e),
//   S_i = sum_j exp2(C1*d_ij), dp_i = C1 * d_{i, i^B}.
// zb stores sqrt(C1)*zhat in bf16, pre-swizzled into MFMA fragment order:
// 16B chunk for (tile=row>>4, c, lane=quad*16+t) at uint4 index
//   (tile*4+c)*64 + lane, covering row=tile*16+t, k in [c*32+quad*8, +8).
// R7: R6 (triangular, -49% FLOPs) was NULL (+2.7us) -> nt_sim ~5us, the
// non-fill budget is dispatch/tail overhead. Revert sim to the proven R5
// full-matrix structure and FUSE finalize into sim via per-row-strip ready
// counters: the 32nd col-block of strip y finalizes its 256 rows inline,
// overlapped with remaining sim blocks. Cross-XCD visibility of part[] is
// handled by agent-scope relaxed atomics (sc1 -> coherence point), NOT
// fences (a threadfence's buffer_inv/wbl2 would nuke zb's L2 residency).
// __syncthreads before the ACQ_REL fetch_add drains vmcnt -> part stores
// are globally complete before the flag increments.
// R5 lesson kept: global_load_lds width=16 staging, barrier-free loop.
// R4 lesson kept: launch_bounds(256,2), minimal live registers.

#define NN 8192
#define BHALF 4096
#define DIMK 128

typedef __bf16 bf16x8 __attribute__((ext_vector_type(8)));
typedef float f32x4 __attribute__((ext_vector_type(4)));

#define C1F 2.8853900817779268f   // 2*log2(e)
#define SCALEF 1.6986436f         // sqrt(C1)

// ---------------- Kernel A: normalize, scale by sqrt(C1), swizzle ----------
__global__ __launch_bounds__(256) void nt_normalize(
    const float* __restrict__ zi, const float* __restrict__ zj,
    unsigned int* __restrict__ zb_packed, float* __restrict__ out,
    int* __restrict__ cnt) {
  if (blockIdx.x == 0) {
    if (threadIdx.x == 0) out[0] = 0.0f;      // runs before fused finalize
    if (threadIdx.x < 32) cnt[threadIdx.x] = 0;  // ws is poisoned each iter
  }
  int row = blockIdx.x * 4 + (threadIdx.x >> 6);
  int lane = threadIdx.x & 63;
  const float* src = (row < BHALF) ? (zi + (size_t)row * DIMK)
                                   : (zj + (size_t)(row - BHALF) * DIMK);
  float2 v = ((const float2*)src)[lane];
  float ss = v.x * v.x + v.y * v.y;
#pragma unroll
  for (int off = 32; off >= 1; off >>= 1) ss += __shfl_xor(ss, off, 64);
  float rn = rsqrtf(ss) * SCALEF;
  __hip_bfloat16 h0 = __float2bfloat16(v.x * rn);
  __hip_bfloat16 h1 = __float2bfloat16(v.y * rn);
  unsigned int packed = ((unsigned int)(*(unsigned short*)&h1) << 16) |
                        (*(unsigned short*)&h0);
  int tile = row >> 4, t = row & 15;
  int cq = lane >> 2;               // chunk index 0..15 (= c*4 + quad)
  int c = cq >> 2, quad = cq & 3;
  size_t widx = ((size_t)((tile * 4 + c) * 64 + quad * 16 + t)) * 4 + (lane & 3);
  zb_packed[widx] = packed;
}

// ---------------- Kernel B: sim + exp2 + fused finalize --------------------
// Grid (32,32): blockIdx.x = col-block (256 cols staged in LDS),
// blockIdx.y = row-strip (256 rows). C/D: col=lane&15, row=quad*4+reg.
__device__ __forceinline__ float bf2f(unsigned short s) {
  unsigned int u = (unsigned int)s << 16;
  return __builtin_bit_cast(float, u);
}

__global__ __launch_bounds__(256, 2) void nt_sim(
    const uint4* __restrict__ zbv, float* __restrict__ part,
    int* __restrict__ cnt, float* __restrict__ out) {
  __shared__ uint4 ldsb[4096];  // 64 KiB: B-span for this block's 256 cols
  __shared__ int sdone;
  __shared__ float wsum[4];

  const int lane = threadIdx.x & 63;
  const int wave = threadIdx.x >> 6;
  const int quad = lane >> 4;
  const int t = lane & 15;
  const int row_tile0 = blockIdx.y * 16 + wave * 4;

  // ---- async-stage the 64KB B-span: 64 chunks of 1KB, 16 instrs/wave ----
  {
    const char* gsrc = (const char*)zbv + (size_t)blockIdx.x * 65536;
#pragma unroll
    for (int k = 0; k < 16; ++k) {
      int chunk = k * 4 + wave;
      __builtin_amdgcn_global_load_lds(
          (const __attribute__((address_space(1))) unsigned int*)(
              gsrc + chunk * 1024 + lane * 16),
          (__attribute__((address_space(3))) unsigned int*)(
              (char*)ldsb + chunk * 1024),
          16, 0, 0);
    }
  }

  // ---- A fragments (persistent registers), overlaps with DMA ----
  bf16x8 A[4][4];  // [row-tile][K-chunk]
#pragma unroll
  for (int rt = 0; rt < 4; ++rt)
#pragma unroll
    for (int c = 0; c < 4; ++c)
      A[rt][c] = __builtin_bit_cast(
          bf16x8, zbv[(size_t)((row_tile0 + rt) * 4 + c) * 64 + lane]);

  float sum[4][4];
#pragma unroll
  for (int rt = 0; rt < 4; ++rt)
#pragma unroll
    for (int r = 0; r < 4; ++r) sum[rt][r] = 0.f;

  __syncthreads();  // DMA drain (vmcnt(0)) + join

  // ---- barrier-free compute loop: 16 col-tiles from LDS ----
#pragma unroll 2
  for (int ct = 0; ct < 16; ++ct) {
    f32x4 acc[4];
#pragma unroll
    for (int rt = 0; rt < 4; ++rt) acc[rt] = (f32x4){0.f, 0.f, 0.f, 0.f};
#pragma unroll
    for (int c = 0; c < 4; ++c) {
      bf16x8 bv = __builtin_bit_cast(bf16x8, ldsb[(ct * 4 + c) * 64 + lane]);
#pragma unroll
      for (int rt = 0; rt < 4; ++rt)
        acc[rt] = __builtin_amdgcn_mfma_f32_16x16x32_bf16(A[rt][c], bv,
                                                          acc[rt], 0, 0, 0);
    }
#pragma unroll
    for (int rt = 0; rt < 4; ++rt)
#pragma unroll
      for (int r = 0; r < 4; ++r)
        sum[rt][r] += __builtin_amdgcn_exp2f(acc[rt][r]);
  }

  // reduce over the 16 col-lanes within each quad
#pragma unroll
  for (int off = 8; off >= 1; off >>= 1)
#pragma unroll
    for (int rt = 0; rt < 4; ++rt)
#pragma unroll
      for (int r = 0; r < 4; ++r)
        sum[rt][r] += __shfl_xor(sum[rt][r], off, 16);

  if (t == 0) {
    // agent-scope (sc1) stores: land at the coherence point so the fused
    // finalizer on another XCD can't read poison-fill garbage from its L2.
    float* dst = part + (size_t)blockIdx.x * NN + blockIdx.y * 256 + wave * 64;
#pragma unroll
    for (int rt = 0; rt < 4; ++rt)
#pragma unroll
      for (int r = 0; r < 4; ++r)
        __hip_atomic_store(&dst[rt * 16 + quad * 4 + r], sum[rt][r],
                           __ATOMIC_RELAXED, __HIP_MEMORY_SCOPE_AGENT);
  }

  // ---- ready-counter: last col-block of this row-strip finalizes it ----
  __syncthreads();  // drains vmcnt -> all waves' part stores complete
  if (threadIdx.x == 0) {
    int prev = __hip_atomic_fetch_add(&cnt[blockIdx.y], 1, __ATOMIC_ACQ_REL,
                                      __HIP_MEMORY_SCOPE_AGENT);
    sdone = (prev == 31) ? 1 : 0;
  }
  __syncthreads();
  if (!sdone) return;

  // ---- fused finalize: 256 rows of strip blockIdx.y, 1 row/thread ----
  {
    int i = blockIdx.y * 256 + threadIdx.x;
    int tile = i >> 4, tt = i & 15;
    int p = i ^ BHALF;
    int tilep = p >> 4;
    float S = 0.f;
#pragma unroll
    for (int k = 0; k < 32; ++k)
      S += __hip_atomic_load(&part[(size_t)k * NN + i], __ATOMIC_RELAXED,
                             __HIP_MEMORY_SCOPE_AGENT);
    float dp = 0.f, dd = 0.f;
#pragma unroll
    for (int cq = 0; cq < 16; ++cq) {
      int c = cq >> 2, q = cq & 3;
      uint4 ua = zbv[(size_t)((tile * 4 + c) * 64 + q * 16 + tt)];
      uint4 up = zbv[(size_t)((tilep * 4 + c) * 64 + q * 16 + tt)];
      const unsigned short* pa = (const unsigned short*)&ua;
      const unsigned short* pp = (const unsigned short*)&up;
#pragma unroll
      for (int k = 0; k < 8; ++k) {
        float a = bf2f(pa[k]), pv = bf2f(pp[k]);
        dd = fmaf(a, a, dd);
        dp = fmaf(a, pv, dp);
      }
    }
    float diag = __builtin_amdgcn_exp2f(dd);        // exp2(C1 * d_ii)
    float v = logf(S - diag) - (2.0f / C1F) * dp;   // lse_i - pos_i
#pragma unroll
    for (int off = 32; off >= 1; off >>= 1) v += __shfl_xor(v, off, 64);
    if ((threadIdx.x & 63) == 0) wsum[threadIdx.x >> 6] = v;
    __syncthreads();
    if (threadIdx.x == 0)
      atomicAdd(out,
                (wsum[0] + wsum[1] + wsum[2] + wsum[3]) * (1.0f / (float)NN));
  }
}

extern "C" void kernel_launch(void* const* d_in, const int* in_sizes, int n_in,
                              void* d_out, int out_size, void* d_ws,
                              size_t ws_size, hipStream_t stream) {
  const float* zi = (const float*)d_in[0];
  const float* zj = (const float*)d_in[1];

  // ws: zb swizzled bf16 (2 MiB) | part[32][8192] (1 MiB) | cnt[32]
  unsigned int* zb = (unsigned int*)d_ws;
  float* part = (float*)((char*)d_ws + (2u << 20));
  int* cnt = (int*)((char*)d_ws + (3u << 20));

  nt_normalize<<<NN / 4, 256, 0, stream>>>(zi, zj, zb, (float*)d_out, cnt);

  dim3 grid(32, 32);  // 32 col-blocks x 256 cols, 32 row-strips x 256 rows
  nt_sim<<<grid, 256, 0, stream>>>((const uint4*)zb, part, cnt,
                                   (float*)d_out);
}

// Round 3
// 81.872 us; speedup vs baseline: 1.1409x; 1.1409x over previous
//
#include <hip/hip_runtime.h>
#include <hip/hip_bf16.h>

// NT-Xent (SimCLR) loss, MI355X gfx950.
// loss = (1/N) * sum_i [ ln(S_i - exp2(C1*d_ii)) - (2/C1)*dp_i ]
//   where d = zhat.zhat^T (unit rows), C1 = 2*log2(e),
//   S_i = sum_j exp2(C1*d_ij), dp_i = C1 * d_{i, i^B}.
// zb stores sqrt(C1)*zhat in bf16, pre-swizzled into MFMA fragment order:
// 16B chunk for (tile=row>>4, c, lane=quad*16+t) at uint4 index
//   (tile*4+c)*64 + lane, covering row=tile*16+t, k in [c*32+quad*8, +8).
// R8: R7's counters exposed the real bottleneck. Fused sim ran 47.5us with
// MfmaUtil 13% / VALU 15% / HBM 3.5% -- and VGPR_Count=88 while the wave's
// intended resident state (A[4][4]=64 VGPR + sum 16 + acc 16-32) needs
// ~115. The compiler was re-loading A fragments from global inside the ct
// loop: 16 ct x 64KB/block = ~1GB of redundant L2 traffic ~= 30us. This is
// why R6's -49% FLOPs was null (sim was L2-reload-bound, not FLOP-bound).
// Fix: 8 waves x 512 threads, 2 row-tiles/wave -> A[2][4] = 32 VGPR, total
// live ~80 under a launch_bounds(512,4) 128-VGPR cap; A stays resident.
// Bonus: 16 waves/CU (was 8). Cost: LDS reads double (~512MB, ~7.4us @
// 69TB/s = new floor). R7's agent-scope fusion reverted (ACQ_REL RMW emits
// L2 writeback+invalidate per block -- another ~15us of the regression).
// R5 lesson kept: global_load_lds width=16 staging, barrier-free loop.

#define NN 8192
#define BHALF 4096
#define DIMK 128

typedef __bf16 bf16x8 __attribute__((ext_vector_type(8)));
typedef float f32x4 __attribute__((ext_vector_type(4)));

#define C1F 2.8853900817779268f   // 2*log2(e)
#define SCALEF 1.6986436f         // sqrt(C1)

// ---------------- Kernel A: normalize, scale by sqrt(C1), swizzle ----------
__global__ __launch_bounds__(256) void nt_normalize(
    const float* __restrict__ zi, const float* __restrict__ zj,
    unsigned int* __restrict__ zb_packed, float* __restrict__ out) {
  if (blockIdx.x == 0 && threadIdx.x == 0) out[0] = 0.0f;  // before finalize
  int row = blockIdx.x * 4 + (threadIdx.x >> 6);
  int lane = threadIdx.x & 63;
  const float* src = (row < BHALF) ? (zi + (size_t)row * DIMK)
                                   : (zj + (size_t)(row - BHALF) * DIMK);
  float2 v = ((const float2*)src)[lane];
  float ss = v.x * v.x + v.y * v.y;
#pragma unroll
  for (int off = 32; off >= 1; off >>= 1) ss += __shfl_xor(ss, off, 64);
  float rn = rsqrtf(ss) * SCALEF;
  __hip_bfloat16 h0 = __float2bfloat16(v.x * rn);
  __hip_bfloat16 h1 = __float2bfloat16(v.y * rn);
  unsigned int packed = ((unsigned int)(*(unsigned short*)&h1) << 16) |
                        (*(unsigned short*)&h0);
  int tile = row >> 4, t = row & 15;
  int cq = lane >> 2;               // chunk index 0..15 (= c*4 + quad)
  int c = cq >> 2, quad = cq & 3;
  size_t widx = ((size_t)((tile * 4 + c) * 64 + quad * 16 + t)) * 4 + (lane & 3);
  zb_packed[widx] = packed;
}

// ---------------- Kernel B: streaming sim + exp2 accumulation --------------
// Block = 8 waves x 32 rows = 256 rows; 256 cols (16 tiles) staged in LDS.
// C/D: col=lane&15, row=quad*4+reg.
__global__ __launch_bounds__(512, 4) void nt_sim(
    const uint4* __restrict__ zbv, float* __restrict__ part) {
  __shared__ uint4 ldsb[4096];  // 64 KiB: B-span for this block's 256 cols

  const int lane = threadIdx.x & 63;
  const int wave = threadIdx.x >> 6;      // 0..7
  const int quad = lane >> 4;
  const int t = lane & 15;
  const int row_tile0 = blockIdx.y * 16 + wave * 2;  // 2 row-tiles per wave

  // ---- async-stage the 64KB B-span: 64 chunks of 1KB, 8 instrs/wave ----
  {
    const char* gsrc = (const char*)zbv + (size_t)blockIdx.x * 65536;
#pragma unroll
    for (int k = 0; k < 8; ++k) {
      int chunk = k * 8 + wave;
      __builtin_amdgcn_global_load_lds(
          (const __attribute__((address_space(1))) unsigned int*)(
              gsrc + chunk * 1024 + lane * 16),
          (__attribute__((address_space(3))) unsigned int*)(
              (char*)ldsb + chunk * 1024),
          16, 0, 0);
    }
  }

  // ---- A fragments: 2 row-tiles x 4 K-chunks = 8 uint4 = 32 VGPR ----
  bf16x8 A[2][4];
#pragma unroll
  for (int rt = 0; rt < 2; ++rt)
#pragma unroll
    for (int c = 0; c < 4; ++c)
      A[rt][c] = __builtin_bit_cast(
          bf16x8, zbv[(size_t)((row_tile0 + rt) * 4 + c) * 64 + lane]);

  float sum[2][4];
#pragma unroll
  for (int rt = 0; rt < 2; ++rt)
#pragma unroll
    for (int r = 0; r < 4; ++r) sum[rt][r] = 0.f;

  __syncthreads();  // DMA drain (vmcnt(0)) + join; only barrier in kernel

  // ---- barrier-free compute loop: 16 col-tiles from LDS ----
#pragma unroll 2
  for (int ct = 0; ct < 16; ++ct) {
    f32x4 acc[2];
#pragma unroll
    for (int rt = 0; rt < 2; ++rt) acc[rt] = (f32x4){0.f, 0.f, 0.f, 0.f};
#pragma unroll
    for (int c = 0; c < 4; ++c) {
      bf16x8 bv = __builtin_bit_cast(bf16x8, ldsb[(ct * 4 + c) * 64 + lane]);
#pragma unroll
      for (int rt = 0; rt < 2; ++rt)
        acc[rt] = __builtin_amdgcn_mfma_f32_16x16x32_bf16(A[rt][c], bv,
                                                          acc[rt], 0, 0, 0);
    }
#pragma unroll
    for (int rt = 0; rt < 2; ++rt)
#pragma unroll
      for (int r = 0; r < 4; ++r)
        sum[rt][r] += __builtin_amdgcn_exp2f(acc[rt][r]);
  }

  // reduce over the 16 col-lanes within each quad
#pragma unroll
  for (int off = 8; off >= 1; off >>= 1)
#pragma unroll
    for (int rt = 0; rt < 2; ++rt)
#pragma unroll
      for (int r = 0; r < 4; ++r)
        sum[rt][r] += __shfl_xor(sum[rt][r], off, 16);

  if (t == 0) {
    float* dst = part + (size_t)blockIdx.x * NN + blockIdx.y * 256 + wave * 32;
#pragma unroll
    for (int rt = 0; rt < 2; ++rt)
#pragma unroll
      for (int r = 0; r < 4; ++r)
        dst[rt * 16 + quad * 4 + r] = sum[rt][r];
  }
}

// ---------------- Kernel C: finalize ----------------
__device__ __forceinline__ float bf2f(unsigned short s) {
  unsigned int u = (unsigned int)s << 16;
  return __builtin_bit_cast(float, u);
}

__global__ __launch_bounds__(256) void nt_finalize(
    const uint4* __restrict__ zbv, const float* __restrict__ part,
    float* __restrict__ out) {
  int i = blockIdx.x * 256 + threadIdx.x;
  int tile = i >> 4, t = i & 15;
  int p = i ^ BHALF;
  int tilep = p >> 4;
  float S = 0.f;
#pragma unroll
  for (int k = 0; k < 32; ++k) S += part[(size_t)k * NN + i];
  float dp = 0.f, dd = 0.f;
#pragma unroll
  for (int cq = 0; cq < 16; ++cq) {
    int c = cq >> 2, q = cq & 3;
    uint4 ua = zbv[(size_t)((tile * 4 + c) * 64 + q * 16 + t)];
    uint4 up = zbv[(size_t)((tilep * 4 + c) * 64 + q * 16 + t)];
    const unsigned short* pa = (const unsigned short*)&ua;
    const unsigned short* pp = (const unsigned short*)&up;
#pragma unroll
    for (int k = 0; k < 8; ++k) {
      float a = bf2f(pa[k]), pv = bf2f(pp[k]);
      dd = fmaf(a, a, dd);
      dp = fmaf(a, pv, dp);
    }
  }
  float diag = __builtin_amdgcn_exp2f(dd);        // exp2(C1 * d_ii)
  float v = logf(S - diag) - (2.0f / C1F) * dp;   // lse_i - pos_i
#pragma unroll
  for (int off = 32; off >= 1; off >>= 1) v += __shfl_xor(v, off, 64);
  __shared__ float wsum[4];
  if ((threadIdx.x & 63) == 0) wsum[threadIdx.x >> 6] = v;
  __syncthreads();
  if (threadIdx.x == 0)
    atomicAdd(out, (wsum[0] + wsum[1] + wsum[2] + wsum[3]) * (1.0f / (float)NN));
}

extern "C" void kernel_launch(void* const* d_in, const int* in_sizes, int n_in,
                              void* d_out, int out_size, void* d_ws,
                              size_t ws_size, hipStream_t stream) {
  const float* zi = (const float*)d_in[0];
  const float* zj = (const float*)d_in[1];

  // ws: zb swizzled bf16 (2 MiB) | part[32][8192] (1 MiB)
  unsigned int* zb = (unsigned int*)d_ws;
  float* part = (float*)((char*)d_ws + (2u << 20));

  nt_normalize<<<NN / 4, 256, 0, stream>>>(zi, zj, zb, (float*)d_out);

  dim3 grid(32, 32);  // 32 col-blocks x 256 cols, 32 row-strips x 256 rows
  nt_sim<<<grid, 512, 0, stream>>>((const uint4*)zb, part);

  nt_finalize<<<NN / 256, 256, 0, stream>>>((const uint4*)zb, part,
                                            (float*)d_out);
}